// Round 2
// baseline (802.643 us; speedup 1.0000x reference)
//
#include <hip/hip_runtime.h>
#include <hip/hip_bf16.h>

// MoE SwiGLU FFN, top-2 of 8 experts. N=4096, D_MODEL=2048, D_FF=1408.
// Strategy: route tokens to per-expert slot lists, then two routed bf16 MFMA
// GEMMs (gate+up fused w/ SiLU, then down w/ scored atomic combine).

#define NTOK 4096
#define DMODEL 2048
#define DFF 1408
#define NEXP 8
#define TOPK 2
#define NSLOT (NTOK * TOPK)

#define BM 64
#define BN 64
#define BK 64
#define MAX_TILES 160           // sum ceil(c_e/64) <= 8192/64 + 8 = 136

typedef short bf16x8 __attribute__((ext_vector_type(8)));   // 8 bf16 (4 VGPRs)
typedef float f32x4 __attribute__((ext_vector_type(4)));

// ---------------- routing ----------------
__global__ __launch_bounds__(256) void route_kernel(
    const int* __restrict__ idx, const float* __restrict__ scores,
    int* __restrict__ meta, int* __restrict__ slot_token, float* __restrict__ slot_score)
{
    __shared__ int counts[NEXP];
    __shared__ int cursor[NEXP];
    int t = threadIdx.x;
    if (t < NEXP) counts[t] = 0;
    __syncthreads();
    for (int i = t; i < NSLOT; i += 256) {
        atomicAdd(&counts[idx[i]], 1);
    }
    __syncthreads();
    if (t == 0) {
        int off = 0, nt = 0;
        for (int e = 0; e < NEXP; e++) {
            cursor[e] = off;
            int c = counts[e];
            for (int s = 0; s < c && nt < MAX_TILES; s += BM) {
                meta[1 + nt * 3 + 0] = e;
                meta[1 + nt * 3 + 1] = off + s;          // slot0
                meta[1 + nt * 3 + 2] = min(BM, c - s);   // rows
                nt++;
            }
            off += c;
        }
        meta[0] = nt;
    }
    __syncthreads();
    for (int i = t; i < NSLOT; i += 256) {
        int e = idx[i];
        int pos = atomicAdd(&cursor[e], 1);
        slot_token[pos] = i / TOPK;
        slot_score[pos] = scores[i];
    }
}

// ---------------- GEMM1: h = silu(x@Wg) * (x@Wu), gathered rows ----------------
__global__ __launch_bounds__(256) void moe_gemm1(
    const float* __restrict__ x, const float* __restrict__ Wg, const float* __restrict__ Wu,
    const int* __restrict__ meta, const int* __restrict__ slot_token,
    __hip_bfloat16* __restrict__ h)
{
    int tile = blockIdx.x;
    if (tile >= meta[0]) return;
    const int e     = meta[1 + tile * 3];
    const int slot0 = meta[2 + tile * 3];
    const int rows  = meta[3 + tile * 3];
    const int n0 = blockIdx.y * BN;

    __shared__ __hip_bfloat16 As[BM][72];    // [row][k], stride 144B (16B-aligned)
    __shared__ __hip_bfloat16 Bgs[BN][72];   // transposed: [n][k]
    __shared__ __hip_bfloat16 Bus[BN][72];

    const int tid = threadIdx.x;
    const int lane = tid & 63;
    const int w = tid >> 6;
    const int wm = w >> 1, wn = w & 1;
    const int l15 = lane & 15;
    const int lg = lane >> 4;                // 0..3 k-group

    const float* __restrict__ WgE = Wg + (size_t)e * DMODEL * DFF;
    const float* __restrict__ WuE = Wu + (size_t)e * DMODEL * DFF;

    f32x4 acc_g[2][2] = {};
    f32x4 acc_u[2][2] = {};

    for (int k0 = 0; k0 < DMODEL; k0 += BK) {
        __syncthreads();
        // stage A (gathered x rows), fp32 -> bf16
        #pragma unroll
        for (int j = 0; j < 4; j++) {
            int linear = tid + j * 256;
            int r = linear >> 4;
            int c4 = (linear & 15) * 4;
            int tok = (r < rows) ? slot_token[slot0 + r] : 0;
            float4 v = *reinterpret_cast<const float4*>(&x[(size_t)tok * DMODEL + k0 + c4]);
            As[r][c4 + 0] = (__hip_bfloat16)v.x;
            As[r][c4 + 1] = (__hip_bfloat16)v.y;
            As[r][c4 + 2] = (__hip_bfloat16)v.z;
            As[r][c4 + 3] = (__hip_bfloat16)v.w;
        }
        // stage Bg/Bu transposed, fp32 -> bf16
        #pragma unroll
        for (int j = 0; j < 4; j++) {
            int linear = tid + j * 256;
            int k = linear >> 4;
            int n4 = (linear & 15) * 4;
            float4 vg = *reinterpret_cast<const float4*>(&WgE[(size_t)(k0 + k) * DFF + n0 + n4]);
            Bgs[n4 + 0][k] = (__hip_bfloat16)vg.x;
            Bgs[n4 + 1][k] = (__hip_bfloat16)vg.y;
            Bgs[n4 + 2][k] = (__hip_bfloat16)vg.z;
            Bgs[n4 + 3][k] = (__hip_bfloat16)vg.w;
            float4 vu = *reinterpret_cast<const float4*>(&WuE[(size_t)(k0 + k) * DFF + n0 + n4]);
            Bus[n4 + 0][k] = (__hip_bfloat16)vu.x;
            Bus[n4 + 1][k] = (__hip_bfloat16)vu.y;
            Bus[n4 + 2][k] = (__hip_bfloat16)vu.z;
            Bus[n4 + 3][k] = (__hip_bfloat16)vu.w;
        }
        __syncthreads();
        #pragma unroll
        for (int kk = 0; kk < 2; kk++) {
            bf16x8 a[2], bg[2], bu[2];
            #pragma unroll
            for (int mf = 0; mf < 2; mf++)
                a[mf] = *reinterpret_cast<const bf16x8*>(&As[wm * 32 + mf * 16 + l15][kk * 32 + lg * 8]);
            #pragma unroll
            for (int nf = 0; nf < 2; nf++) {
                bg[nf] = *reinterpret_cast<const bf16x8*>(&Bgs[wn * 32 + nf * 16 + l15][kk * 32 + lg * 8]);
                bu[nf] = *reinterpret_cast<const bf16x8*>(&Bus[wn * 32 + nf * 16 + l15][kk * 32 + lg * 8]);
            }
            #pragma unroll
            for (int mf = 0; mf < 2; mf++)
                #pragma unroll
                for (int nf = 0; nf < 2; nf++) {
                    acc_g[mf][nf] = __builtin_amdgcn_mfma_f32_16x16x32_bf16(a[mf], bg[nf], acc_g[mf][nf], 0, 0, 0);
                    acc_u[mf][nf] = __builtin_amdgcn_mfma_f32_16x16x32_bf16(a[mf], bu[nf], acc_u[mf][nf], 0, 0, 0);
                }
        }
    }

    // epilogue: SiLU(gate) * up -> h[slot][n]  (C layout: row=(lane>>4)*4+j, col=lane&15)
    #pragma unroll
    for (int mf = 0; mf < 2; mf++)
        #pragma unroll
        for (int nf = 0; nf < 2; nf++)
            #pragma unroll
            for (int j = 0; j < 4; j++) {
                int r = wm * 32 + mf * 16 + lg * 4 + j;
                int c = wn * 32 + nf * 16 + l15;
                if (r < rows) {
                    float g = acc_g[mf][nf][j];
                    float u = acc_u[mf][nf][j];
                    float hv = g / (1.0f + __expf(-g)) * u;
                    h[(size_t)(slot0 + r) * DFF + n0 + c] = (__hip_bfloat16)hv;
                }
            }
}

// ---------------- GEMM2: out[tok] += score * (h @ Wd) ----------------
__global__ __launch_bounds__(256) void moe_gemm2(
    const __hip_bfloat16* __restrict__ h, const float* __restrict__ Wd,
    const int* __restrict__ meta, const int* __restrict__ slot_token,
    const float* __restrict__ slot_score, float* __restrict__ out)
{
    int tile = blockIdx.x;
    if (tile >= meta[0]) return;
    const int e     = meta[1 + tile * 3];
    const int slot0 = meta[2 + tile * 3];
    const int rows  = meta[3 + tile * 3];
    const int n0 = blockIdx.y * BN;

    __shared__ __hip_bfloat16 As[BM][72];
    __shared__ __hip_bfloat16 Bs[BN][72];    // transposed: [n][k]

    const int tid = threadIdx.x;
    const int lane = tid & 63;
    const int w = tid >> 6;
    const int wm = w >> 1, wn = w & 1;
    const int l15 = lane & 15;
    const int lg = lane >> 4;

    const float* __restrict__ WdE = Wd + (size_t)e * DFF * DMODEL;

    f32x4 acc[2][2] = {};

    for (int k0 = 0; k0 < DFF; k0 += BK) {   // 22 iters
        __syncthreads();
        // stage A from h (already bf16): 16B per thread x2
        #pragma unroll
        for (int j = 0; j < 2; j++) {
            int linear = tid + j * 256;
            int r = linear >> 3;
            int c8 = (linear & 7) * 8;
            bf16x8 v = *reinterpret_cast<const bf16x8*>(&h[(size_t)(slot0 + r) * DFF + k0 + c8]);
            *reinterpret_cast<bf16x8*>(&As[r][c8]) = v;
        }
        // stage B transposed, fp32 -> bf16
        #pragma unroll
        for (int j = 0; j < 4; j++) {
            int linear = tid + j * 256;
            int k = linear >> 4;
            int n4 = (linear & 15) * 4;
            float4 v = *reinterpret_cast<const float4*>(&WdE[(size_t)(k0 + k) * DMODEL + n0 + n4]);
            Bs[n4 + 0][k] = (__hip_bfloat16)v.x;
            Bs[n4 + 1][k] = (__hip_bfloat16)v.y;
            Bs[n4 + 2][k] = (__hip_bfloat16)v.z;
            Bs[n4 + 3][k] = (__hip_bfloat16)v.w;
        }
        __syncthreads();
        #pragma unroll
        for (int kk = 0; kk < 2; kk++) {
            bf16x8 a[2], b[2];
            #pragma unroll
            for (int mf = 0; mf < 2; mf++)
                a[mf] = *reinterpret_cast<const bf16x8*>(&As[wm * 32 + mf * 16 + l15][kk * 32 + lg * 8]);
            #pragma unroll
            for (int nf = 0; nf < 2; nf++)
                b[nf] = *reinterpret_cast<const bf16x8*>(&Bs[wn * 32 + nf * 16 + l15][kk * 32 + lg * 8]);
            #pragma unroll
            for (int mf = 0; mf < 2; mf++)
                #pragma unroll
                for (int nf = 0; nf < 2; nf++)
                    acc[mf][nf] = __builtin_amdgcn_mfma_f32_16x16x32_bf16(a[mf], b[nf], acc[mf][nf], 0, 0, 0);
        }
    }

    // epilogue: weighted atomic combine into out[token]
    #pragma unroll
    for (int mf = 0; mf < 2; mf++)
        #pragma unroll
        for (int nf = 0; nf < 2; nf++)
            #pragma unroll
            for (int j = 0; j < 4; j++) {
                int r = wm * 32 + mf * 16 + lg * 4 + j;
                int c = wn * 32 + nf * 16 + l15;
                if (r < rows) {
                    int slot = slot0 + r;
                    int tok = slot_token[slot];
                    float s = slot_score[slot];
                    atomicAdd(&out[(size_t)tok * DMODEL + n0 + c], acc[mf][nf][j] * s);
                }
            }
}

extern "C" void kernel_launch(void* const* d_in, const int* in_sizes, int n_in,
                              void* d_out, int out_size, void* d_ws, size_t ws_size,
                              hipStream_t stream) {
    const float* x      = (const float*)d_in[0];
    const int*   idx    = (const int*)d_in[1];
    const float* scores = (const float*)d_in[2];
    const float* Wg     = (const float*)d_in[3];
    const float* Wu     = (const float*)d_in[4];
    const float* Wd     = (const float*)d_in[5];
    float* out = (float*)d_out;

    // ws layout (~24 MB total):
    char* ws = (char*)d_ws;
    int*   meta       = (int*)ws;                       // 1 + 3*MAX_TILES ints
    int*   slot_token = (int*)(ws + 4096);              // 8448 ints
    float* slot_score = (float*)(ws + 4096 + 34816);    // 8448 floats
    __hip_bfloat16* h = (__hip_bfloat16*)(ws + 81920);  // 8448 x 1408 bf16 (padded rows)

    hipMemsetAsync(d_out, 0, (size_t)NTOK * DMODEL * sizeof(float), stream);

    route_kernel<<<1, 256, 0, stream>>>(idx, scores, meta, slot_token, slot_score);

    dim3 g1(NSLOT / BM + NEXP, DFF / BN);     // 136 x 22
    moe_gemm1<<<g1, 256, 0, stream>>>(x, Wg, Wu, meta, slot_token, h);

    dim3 g2(NSLOT / BM + NEXP, DMODEL / BN);  // 136 x 32
    moe_gemm2<<<g2, 256, 0, stream>>>(h, Wd, meta, slot_token, slot_score, out);
}

// Round 3
// 463.320 us; speedup vs baseline: 1.7324x; 1.7324x over previous
//
#include <hip/hip_runtime.h>
#include <hip/hip_bf16.h>

// MoE SwiGLU FFN, top-2 of 8 experts. N=4096, D_MODEL=2048, D_FF=1408.
// Fast path: pre-convert x -> bf16 and weights -> transposed bf16 [n][k] in ws,
// then m97-structure GEMMs (global_load_lds width-16 staging, 128-row tiles,
// bf16 MFMA 16x16x32). Fallback (ws too small): round-2 in-loop-convert GEMMs.

#define NTOK 4096
#define DMODEL 2048
#define DFF 1408
#define NEXP 8
#define TOPK 2
#define NSLOT (NTOK * TOPK)
#define MAX_TILES 160

typedef short bf16x8 __attribute__((ext_vector_type(8)));
typedef float f32x4 __attribute__((ext_vector_type(4)));

__device__ inline void async16(const void* g, void* l) {
    __builtin_amdgcn_global_load_lds(
        (const __attribute__((address_space(1))) void*)g,
        (__attribute__((address_space(3))) void*)l, 16, 0, 0);
}

// ---------------- routing ----------------
__global__ __launch_bounds__(256) void route_kernel(
    const int* __restrict__ idx, const float* __restrict__ scores,
    int* __restrict__ meta, int* __restrict__ slot_token, float* __restrict__ slot_score,
    int bm)
{
    __shared__ int counts[NEXP];
    __shared__ int cursor[NEXP];
    int t = threadIdx.x;
    if (t < NEXP) counts[t] = 0;
    __syncthreads();
    for (int i = t; i < NSLOT; i += 256) atomicAdd(&counts[idx[i]], 1);
    __syncthreads();
    if (t == 0) {
        int off = 0, nt = 0;
        for (int e = 0; e < NEXP; e++) {
            cursor[e] = off;
            int c = counts[e];
            for (int s = 0; s < c && nt < MAX_TILES; s += bm) {
                meta[1 + nt * 3 + 0] = e;
                meta[1 + nt * 3 + 1] = off + s;
                meta[1 + nt * 3 + 2] = min(bm, c - s);
                nt++;
            }
            off += c;
        }
        meta[0] = nt;
    }
    __syncthreads();
    for (int i = t; i < NSLOT; i += 256) {
        int e = idx[i];
        int pos = atomicAdd(&cursor[e], 1);
        slot_token[pos] = i / TOPK;
        slot_score[pos] = scores[i];
    }
}

// ---------------- pre-pass: x fp32 -> bf16 ----------------
__global__ __launch_bounds__(256) void convert_x(
    const float* __restrict__ x, __hip_bfloat16* __restrict__ xb)
{
    int i = blockIdx.x * 256 + threadIdx.x;       // one float4 per thread
    float4 v = reinterpret_cast<const float4*>(x)[i];
    __hip_bfloat16 o[4] = {(__hip_bfloat16)v.x, (__hip_bfloat16)v.y,
                           (__hip_bfloat16)v.z, (__hip_bfloat16)v.w};
    *reinterpret_cast<uint2*>(&xb[(size_t)i * 4]) = *reinterpret_cast<uint2*>(o);
}

// ---------------- pre-pass: per-expert fp32 [R][C] -> bf16 [C][R] ----------------
__global__ __launch_bounds__(256) void transpose_convert(
    const float* __restrict__ in, __hip_bfloat16* __restrict__ out, int R, int C)
{
    __shared__ __hip_bfloat16 t[64][68];          // 136B rows: 4-way write, ~2-way read
    const size_t base = (size_t)blockIdx.z * R * C;
    const int c0 = blockIdx.x * 64, r0 = blockIdx.y * 64;
    const int tid = threadIdx.x;
    const int rl = tid >> 4, c4 = (tid & 15) * 4;
    #pragma unroll
    for (int j = 0; j < 4; j++) {
        int r = rl + j * 16;
        float4 v = *reinterpret_cast<const float4*>(&in[base + (size_t)(r0 + r) * C + c0 + c4]);
        t[c4 + 0][r] = (__hip_bfloat16)v.x;
        t[c4 + 1][r] = (__hip_bfloat16)v.y;
        t[c4 + 2][r] = (__hip_bfloat16)v.z;
        t[c4 + 3][r] = (__hip_bfloat16)v.w;
    }
    __syncthreads();
    const int nl = tid >> 3, k8 = (tid & 7) * 8;
    #pragma unroll
    for (int j = 0; j < 2; j++) {
        int n = nl + j * 32;
        const uint* p = reinterpret_cast<const uint*>(&t[n][k8]);
        uint4 o = {p[0], p[1], p[2], p[3]};
        *reinterpret_cast<uint4*>(&out[base + (size_t)(c0 + n) * R + r0 + k8]) = o;
    }
}

// ---------------- fast GEMM1: h = silu(x@Wg)*(x@Wu), m97 structure ----------------
// BM=128 rows, 64 cols of gate+up per block. 4 waves, wave = 64 rows x 32 cols.
__global__ __launch_bounds__(256) void moe_gemm1_fast(
    const __hip_bfloat16* __restrict__ xb,
    const __hip_bfloat16* __restrict__ WgT, const __hip_bfloat16* __restrict__ WuT,
    const int* __restrict__ meta, const int* __restrict__ slot_token,
    __hip_bfloat16* __restrict__ h)
{
    int tile = blockIdx.x;
    if (tile >= meta[0]) return;
    const int e = meta[1 + tile * 3], slot0 = meta[2 + tile * 3], rows = meta[3 + tile * 3];
    const int gn0 = blockIdx.y * 64;

    __shared__ __hip_bfloat16 As[128][64];
    __shared__ __hip_bfloat16 Bgs[64][64];
    __shared__ __hip_bfloat16 Bus[64][64];

    const int tid = threadIdx.x, lane = tid & 63, w = tid >> 6;
    const int wm = w >> 1, wn = w & 1, l15 = lane & 15, lg = lane >> 4;
    const int lr = lane >> 3, lk = (lane & 7) * 8;

    const __hip_bfloat16* asrc[4];
    #pragma unroll
    for (int i = 0; i < 4; i++) {
        int r = w * 32 + i * 8 + lr;
        int slot = slot0 + (r < rows ? r : 0);
        asrc[i] = xb + (size_t)slot_token[slot] * DMODEL + lk;
    }
    const __hip_bfloat16* bgsrc[2];
    const __hip_bfloat16* busrc[2];
    #pragma unroll
    for (int i = 0; i < 2; i++) {
        int n = w * 16 + i * 8 + lr;
        bgsrc[i] = WgT + ((size_t)e * DFF + gn0 + n) * DMODEL + lk;
        busrc[i] = WuT + ((size_t)e * DFF + gn0 + n) * DMODEL + lk;
    }
    char* alds = (char*)&As[w * 32][0];
    char* bglds = (char*)&Bgs[w * 16][0];
    char* bulds = (char*)&Bus[w * 16][0];

    f32x4 ag[4][2] = {};
    f32x4 au[4][2] = {};

    for (int k0 = 0; k0 < DMODEL; k0 += 64) {
        #pragma unroll
        for (int i = 0; i < 4; i++) async16(asrc[i] + k0, alds + i * 1024);
        #pragma unroll
        for (int i = 0; i < 2; i++) {
            async16(bgsrc[i] + k0, bglds + i * 1024);
            async16(busrc[i] + k0, bulds + i * 1024);
        }
        __syncthreads();   // compiler drains vmcnt before s_barrier
        #pragma unroll
        for (int kk = 0; kk < 2; kk++) {
            bf16x8 a[4], bg[2], bu[2];
            #pragma unroll
            for (int mf = 0; mf < 4; mf++)
                a[mf] = *reinterpret_cast<const bf16x8*>(&As[wm * 64 + mf * 16 + l15][kk * 32 + lg * 8]);
            #pragma unroll
            for (int nf = 0; nf < 2; nf++) {
                bg[nf] = *reinterpret_cast<const bf16x8*>(&Bgs[wn * 32 + nf * 16 + l15][kk * 32 + lg * 8]);
                bu[nf] = *reinterpret_cast<const bf16x8*>(&Bus[wn * 32 + nf * 16 + l15][kk * 32 + lg * 8]);
            }
            #pragma unroll
            for (int mf = 0; mf < 4; mf++)
                #pragma unroll
                for (int nf = 0; nf < 2; nf++) {
                    ag[mf][nf] = __builtin_amdgcn_mfma_f32_16x16x32_bf16(a[mf], bg[nf], ag[mf][nf], 0, 0, 0);
                    au[mf][nf] = __builtin_amdgcn_mfma_f32_16x16x32_bf16(a[mf], bu[nf], au[mf][nf], 0, 0, 0);
                }
        }
        __syncthreads();
    }

    #pragma unroll
    for (int mf = 0; mf < 4; mf++) {
        #pragma unroll
        for (int j = 0; j < 4; j++) {
            int r = wm * 64 + mf * 16 + lg * 4 + j;
            if (r < rows) {
                size_t hrow = (size_t)(slot0 + r) * DFF + gn0 + wn * 32;
                #pragma unroll
                for (int nf = 0; nf < 2; nf++) {
                    float g = ag[mf][nf][j], u = au[mf][nf][j];
                    float hv = g / (1.0f + __expf(-g)) * u;
                    h[hrow + nf * 16 + l15] = (__hip_bfloat16)hv;
                }
            }
        }
    }
}

// ---------------- fast GEMM2: out[tok] += score * (h @ Wd) ----------------
// BM=128, BN=128. 4 waves, wave = 64x64, acc[4][4].
__global__ __launch_bounds__(256) void moe_gemm2_fast(
    const __hip_bfloat16* __restrict__ h, const __hip_bfloat16* __restrict__ WdT,
    const int* __restrict__ meta, const int* __restrict__ slot_token,
    const float* __restrict__ slot_score, float* __restrict__ out)
{
    int tile = blockIdx.x;
    if (tile >= meta[0]) return;
    const int e = meta[1 + tile * 3], slot0 = meta[2 + tile * 3], rows = meta[3 + tile * 3];
    const int n0 = blockIdx.y * 128;

    __shared__ __hip_bfloat16 Ah[128][64];
    __shared__ __hip_bfloat16 Bd[128][64];

    const int tid = threadIdx.x, lane = tid & 63, w = tid >> 6;
    const int wm = w >> 1, wn = w & 1, l15 = lane & 15, lg = lane >> 4;
    const int lr = lane >> 3, lk = (lane & 7) * 8;

    const __hip_bfloat16* asrc[4];
    const __hip_bfloat16* bsrc[4];
    #pragma unroll
    for (int i = 0; i < 4; i++) {
        int r = (w * 4 + i) * 8 + lr;
        int slot = slot0 + (r < rows ? r : 0);
        asrc[i] = h + (size_t)slot * DFF + lk;
        bsrc[i] = WdT + ((size_t)e * DMODEL + n0 + r) * DFF + lk;
    }
    char* alds = (char*)&Ah[w * 32][0];
    char* blds = (char*)&Bd[w * 32][0];

    f32x4 acc[4][4] = {};

    for (int k0 = 0; k0 < DFF; k0 += 64) {   // 22 steps
        #pragma unroll
        for (int i = 0; i < 4; i++) {
            async16(asrc[i] + k0, alds + i * 1024);
            async16(bsrc[i] + k0, blds + i * 1024);
        }
        __syncthreads();
        #pragma unroll
        for (int kk = 0; kk < 2; kk++) {
            bf16x8 a[4], b[4];
            #pragma unroll
            for (int mf = 0; mf < 4; mf++)
                a[mf] = *reinterpret_cast<const bf16x8*>(&Ah[wm * 64 + mf * 16 + l15][kk * 32 + lg * 8]);
            #pragma unroll
            for (int nf = 0; nf < 4; nf++)
                b[nf] = *reinterpret_cast<const bf16x8*>(&Bd[wn * 64 + nf * 16 + l15][kk * 32 + lg * 8]);
            #pragma unroll
            for (int mf = 0; mf < 4; mf++)
                #pragma unroll
                for (int nf = 0; nf < 4; nf++)
                    acc[mf][nf] = __builtin_amdgcn_mfma_f32_16x16x32_bf16(a[mf], b[nf], acc[mf][nf], 0, 0, 0);
        }
        __syncthreads();
    }

    #pragma unroll
    for (int mf = 0; mf < 4; mf++) {
        #pragma unroll
        for (int j = 0; j < 4; j++) {
            int r = wm * 64 + mf * 16 + lg * 4 + j;
            if (r < rows) {
                int slot = slot0 + r;
                int tok = slot_token[slot];
                float s = slot_score[slot];
                float* orow = out + (size_t)tok * DMODEL + n0 + wn * 64;
                #pragma unroll
                for (int nf = 0; nf < 4; nf++)
                    atomicAdd(&orow[nf * 16 + l15], s * acc[mf][nf][j]);
            }
        }
    }
}

// ================= fallback (round-2) kernels =================
__global__ __launch_bounds__(256) void moe_gemm1(
    const float* __restrict__ x, const float* __restrict__ Wg, const float* __restrict__ Wu,
    const int* __restrict__ meta, const int* __restrict__ slot_token,
    __hip_bfloat16* __restrict__ h)
{
    int tile = blockIdx.x;
    if (tile >= meta[0]) return;
    const int e = meta[1 + tile * 3], slot0 = meta[2 + tile * 3], rows = meta[3 + tile * 3];
    const int n0 = blockIdx.y * 64;
    __shared__ __hip_bfloat16 As[64][72];
    __shared__ __hip_bfloat16 Bgs[64][72];
    __shared__ __hip_bfloat16 Bus[64][72];
    const int tid = threadIdx.x, lane = tid & 63, w = tid >> 6;
    const int wm = w >> 1, wn = w & 1, l15 = lane & 15, lg = lane >> 4;
    const float* __restrict__ WgE = Wg + (size_t)e * DMODEL * DFF;
    const float* __restrict__ WuE = Wu + (size_t)e * DMODEL * DFF;
    f32x4 acc_g[2][2] = {};
    f32x4 acc_u[2][2] = {};
    for (int k0 = 0; k0 < DMODEL; k0 += 64) {
        __syncthreads();
        #pragma unroll
        for (int j = 0; j < 4; j++) {
            int linear = tid + j * 256;
            int r = linear >> 4, c4 = (linear & 15) * 4;
            int tok = (r < rows) ? slot_token[slot0 + r] : 0;
            float4 v = *reinterpret_cast<const float4*>(&x[(size_t)tok * DMODEL + k0 + c4]);
            As[r][c4 + 0] = (__hip_bfloat16)v.x; As[r][c4 + 1] = (__hip_bfloat16)v.y;
            As[r][c4 + 2] = (__hip_bfloat16)v.z; As[r][c4 + 3] = (__hip_bfloat16)v.w;
        }
        #pragma unroll
        for (int j = 0; j < 4; j++) {
            int linear = tid + j * 256;
            int k = linear >> 4, n4 = (linear & 15) * 4;
            float4 vg = *reinterpret_cast<const float4*>(&WgE[(size_t)(k0 + k) * DFF + n0 + n4]);
            Bgs[n4 + 0][k] = (__hip_bfloat16)vg.x; Bgs[n4 + 1][k] = (__hip_bfloat16)vg.y;
            Bgs[n4 + 2][k] = (__hip_bfloat16)vg.z; Bgs[n4 + 3][k] = (__hip_bfloat16)vg.w;
            float4 vu = *reinterpret_cast<const float4*>(&WuE[(size_t)(k0 + k) * DFF + n0 + n4]);
            Bus[n4 + 0][k] = (__hip_bfloat16)vu.x; Bus[n4 + 1][k] = (__hip_bfloat16)vu.y;
            Bus[n4 + 2][k] = (__hip_bfloat16)vu.z; Bus[n4 + 3][k] = (__hip_bfloat16)vu.w;
        }
        __syncthreads();
        #pragma unroll
        for (int kk = 0; kk < 2; kk++) {
            bf16x8 a[2], bg[2], bu[2];
            #pragma unroll
            for (int mf = 0; mf < 2; mf++)
                a[mf] = *reinterpret_cast<const bf16x8*>(&As[wm * 32 + mf * 16 + l15][kk * 32 + lg * 8]);
            #pragma unroll
            for (int nf = 0; nf < 2; nf++) {
                bg[nf] = *reinterpret_cast<const bf16x8*>(&Bgs[wn * 32 + nf * 16 + l15][kk * 32 + lg * 8]);
                bu[nf] = *reinterpret_cast<const bf16x8*>(&Bus[wn * 32 + nf * 16 + l15][kk * 32 + lg * 8]);
            }
            #pragma unroll
            for (int mf = 0; mf < 2; mf++)
                #pragma unroll
                for (int nf = 0; nf < 2; nf++) {
                    acc_g[mf][nf] = __builtin_amdgcn_mfma_f32_16x16x32_bf16(a[mf], bg[nf], acc_g[mf][nf], 0, 0, 0);
                    acc_u[mf][nf] = __builtin_amdgcn_mfma_f32_16x16x32_bf16(a[mf], bu[nf], acc_u[mf][nf], 0, 0, 0);
                }
        }
    }
    #pragma unroll
    for (int mf = 0; mf < 2; mf++)
        #pragma unroll
        for (int nf = 0; nf < 2; nf++)
            #pragma unroll
            for (int j = 0; j < 4; j++) {
                int r = wm * 32 + mf * 16 + lg * 4 + j;
                int c = wn * 32 + nf * 16 + l15;
                if (r < rows) {
                    float g = acc_g[mf][nf][j], u = acc_u[mf][nf][j];
                    h[(size_t)(slot0 + r) * DFF + n0 + c] = (__hip_bfloat16)(g / (1.0f + __expf(-g)) * u);
                }
            }
}

__global__ __launch_bounds__(256) void moe_gemm2(
    const __hip_bfloat16* __restrict__ h, const float* __restrict__ Wd,
    const int* __restrict__ meta, const int* __restrict__ slot_token,
    const float* __restrict__ slot_score, float* __restrict__ out)
{
    int tile = blockIdx.x;
    if (tile >= meta[0]) return;
    const int e = meta[1 + tile * 3], slot0 = meta[2 + tile * 3], rows = meta[3 + tile * 3];
    const int n0 = blockIdx.y * 64;
    __shared__ __hip_bfloat16 As[64][72];
    __shared__ __hip_bfloat16 Bs[64][72];
    const int tid = threadIdx.x, lane = tid & 63, w = tid >> 6;
    const int wm = w >> 1, wn = w & 1, l15 = lane & 15, lg = lane >> 4;
    const float* __restrict__ WdE = Wd + (size_t)e * DFF * DMODEL;
    f32x4 acc[2][2] = {};
    for (int k0 = 0; k0 < DFF; k0 += 64) {
        __syncthreads();
        #pragma unroll
        for (int j = 0; j < 2; j++) {
            int linear = tid + j * 256;
            int r = linear >> 3, c8 = (linear & 7) * 8;
            bf16x8 v = *reinterpret_cast<const bf16x8*>(&h[(size_t)(slot0 + r) * DFF + k0 + c8]);
            *reinterpret_cast<bf16x8*>(&As[r][c8]) = v;
        }
        #pragma unroll
        for (int j = 0; j < 4; j++) {
            int linear = tid + j * 256;
            int k = linear >> 4, n4 = (linear & 15) * 4;
            float4 v = *reinterpret_cast<const float4*>(&WdE[(size_t)(k0 + k) * DMODEL + n0 + n4]);
            Bs[n4 + 0][k] = (__hip_bfloat16)v.x; Bs[n4 + 1][k] = (__hip_bfloat16)v.y;
            Bs[n4 + 2][k] = (__hip_bfloat16)v.z; Bs[n4 + 3][k] = (__hip_bfloat16)v.w;
        }
        __syncthreads();
        #pragma unroll
        for (int kk = 0; kk < 2; kk++) {
            bf16x8 a[2], b[2];
            #pragma unroll
            for (int mf = 0; mf < 2; mf++)
                a[mf] = *reinterpret_cast<const bf16x8*>(&As[wm * 32 + mf * 16 + l15][kk * 32 + lg * 8]);
            #pragma unroll
            for (int nf = 0; nf < 2; nf++)
                b[nf] = *reinterpret_cast<const bf16x8*>(&Bs[wn * 32 + nf * 16 + l15][kk * 32 + lg * 8]);
            #pragma unroll
            for (int mf = 0; mf < 2; mf++)
                #pragma unroll
                for (int nf = 0; nf < 2; nf++)
                    acc[mf][nf] = __builtin_amdgcn_mfma_f32_16x16x32_bf16(a[mf], b[nf], acc[mf][nf], 0, 0, 0);
        }
    }
    #pragma unroll
    for (int mf = 0; mf < 2; mf++)
        #pragma unroll
        for (int nf = 0; nf < 2; nf++)
            #pragma unroll
            for (int j = 0; j < 4; j++) {
                int r = wm * 32 + mf * 16 + lg * 4 + j;
                int c = wn * 32 + nf * 16 + l15;
                if (r < rows) {
                    int slot = slot0 + r;
                    atomicAdd(&out[(size_t)slot_token[slot] * DMODEL + n0 + c],
                              acc[mf][nf][j] * slot_score[slot]);
                }
            }
}

extern "C" void kernel_launch(void* const* d_in, const int* in_sizes, int n_in,
                              void* d_out, int out_size, void* d_ws, size_t ws_size,
                              hipStream_t stream) {
    const float* x      = (const float*)d_in[0];
    const int*   idx    = (const int*)d_in[1];
    const float* scores = (const float*)d_in[2];
    const float* Wg     = (const float*)d_in[3];
    const float* Wu     = (const float*)d_in[4];
    const float* Wd     = (const float*)d_in[5];
    float* out = (float*)d_out;

    char* ws = (char*)d_ws;
    int*   meta       = (int*)ws;
    int*   slot_token = (int*)(ws + 4096);
    float* slot_score = (float*)(ws + 4096 + 34816);

    // fast-path ws layout
    const size_t XB_OFF = (size_t)1 << 20;
    const size_t HB_OFF = (size_t)20 << 20;
    const size_t WG_OFF = (size_t)44 << 20;
    const size_t WU_OFF = (size_t)92 << 20;
    const size_t WD_OFF = (size_t)140 << 20;
    const size_t NEED   = (size_t)187 << 20;
    const bool fast = ws_size >= NEED;

    hipMemsetAsync(d_out, 0, (size_t)NTOK * DMODEL * sizeof(float), stream);
    route_kernel<<<1, 256, 0, stream>>>(idx, scores, meta, slot_token, slot_score, fast ? 128 : 64);

    if (fast) {
        __hip_bfloat16* xb  = (__hip_bfloat16*)(ws + XB_OFF);
        __hip_bfloat16* hb  = (__hip_bfloat16*)(ws + HB_OFF);
        __hip_bfloat16* WgT = (__hip_bfloat16*)(ws + WG_OFF);
        __hip_bfloat16* WuT = (__hip_bfloat16*)(ws + WU_OFF);
        __hip_bfloat16* WdT = (__hip_bfloat16*)(ws + WD_OFF);

        convert_x<<<(NTOK * DMODEL / 4) / 256, 256, 0, stream>>>(x, xb);
        dim3 tg(DFF / 64, DMODEL / 64, NEXP);     // R=DMODEL, C=DFF
        transpose_convert<<<tg, 256, 0, stream>>>(Wg, WgT, DMODEL, DFF);
        transpose_convert<<<tg, 256, 0, stream>>>(Wu, WuT, DMODEL, DFF);
        dim3 td(DMODEL / 64, DFF / 64, NEXP);     // R=DFF, C=DMODEL
        transpose_convert<<<td, 256, 0, stream>>>(Wd, WdT, DFF, DMODEL);

        dim3 g1(NSLOT / 128 + NEXP, DFF / 64);    // 72 x 22
        moe_gemm1_fast<<<g1, 256, 0, stream>>>(xb, WgT, WuT, meta, slot_token, hb);
        dim3 g2(NSLOT / 128 + NEXP, DMODEL / 128); // 72 x 16
        moe_gemm2_fast<<<g2, 256, 0, stream>>>(hb, WdT, meta, slot_token, slot_score, out);
    } else {
        __hip_bfloat16* hb = (__hip_bfloat16*)(ws + 81920);
        dim3 g1(NSLOT / 64 + NEXP, DFF / 64);
        moe_gemm1<<<g1, 256, 0, stream>>>(x, Wg, Wu, meta, slot_token, hb);
        dim3 g2(NSLOT / 64 + NEXP, DMODEL / 64);
        moe_gemm2<<<g2, 256, 0, stream>>>(hb, Wd, meta, slot_token, slot_score, out);
    }
}